// Round 3
// baseline (188.191 us; speedup 1.0000x reference)
//
#include <hip/hip_runtime.h>
#include <hip/hip_fp16.h>
#include <stdint.h>

// Problem constants: Xp(16384,3) X(8192,3) W(64,8192) eps scalar -> out(16384,64)
#define M_ROWS 16384
#define N_PTS  8192
#define K_OUT  64

typedef _Float16       h2    __attribute__((ext_vector_type(2)));
typedef unsigned short u16x2 __attribute__((ext_vector_type(2)));
typedef _Float16       f16x8 __attribute__((ext_vector_type(8)));
typedef float          f32x4 __attribute__((ext_vector_type(4)));

union AF { f16x8 v; uint4 q; uint32_t u[4]; h2 h[4]; };

__device__ __forceinline__ h2 pkrtz2(float a, float b) {
    return __builtin_bit_cast(h2, __builtin_amdgcn_cvt_pkrtz(a, b));
}
__device__ __forceinline__ uint32_t pkrtz(float a, float b) {
    return __builtin_bit_cast(uint32_t, __builtin_amdgcn_cvt_pkrtz(a, b));
}

// packed fast sqrt(t), t in [1, ~512]: per-half rsqrt bit-seed (0x59BA - (u>>1),
// packed 16-bit ops so no cross-half contamination) + 1 reassociated Newton:
// y = t*r0; p = y*r0; k = 1.5 - 0.5*p; phi = y*k.  6 packed VALU ops / 2 phis.
// Rel err <= ~3e-3 (validated: absmax 8 vs threshold 21.28).
__device__ __forceinline__ h2 pk_sqrt_fast(h2 t, h2 mhf, h2 c15) {
    u16x2 u = __builtin_bit_cast(u16x2, t);
    u16x2 r0u = (u16x2){0x59BA, 0x59BA} - (u >> 1);
    h2 r0 = __builtin_bit_cast(h2, r0u);
    h2 y = t * r0;
    h2 p = y * r0;
    h2 k = __builtin_elementwise_fma(p, mhf, c15);
    return y * k;
}

// ---------------- prep ----------------
// blocks [0,256):   W -> fragment-linear f16 Wt (B-frag order for 16x16x32):
//                   Wt uint4 idx (b*4+kt)*64+lane = W[kt*16+(lane&15)][b*32+(lane>>4)*8+j]
// blocks [256,272): coord streams as packed-f16 pairs (4096 dwords each):
//                   Cx = -2*eps*x, Cy, Cz, Cc = |eps*x|^2 + 1
__global__ __launch_bounds__(256) void rbf_prep(
    const float* __restrict__ Wf, const float* __restrict__ X,
    const float* __restrict__ epsp,
    uint4* __restrict__ Wt, uint32_t* __restrict__ Cx,
    uint32_t* __restrict__ Cy, uint32_t* __restrict__ Cz,
    uint32_t* __restrict__ Cc)
{
    const int bid = blockIdx.x, tid = threadIdx.x;
    if (bid < 256) {
        const int kt = tid >> 6, lane = tid & 63;
        const int l15 = lane & 15, g = lane >> 4;
        const int row = kt * 16 + l15;
        const int col = bid * 32 + g * 8;
        const float4* src = (const float4*)(Wf + row * N_PTS + col);
        const float4 w0 = src[0], w1 = src[1];
        uint4 p;
        p.x = pkrtz(w0.x, w0.y);
        p.y = pkrtz(w0.z, w0.w);
        p.z = pkrtz(w1.x, w1.y);
        p.w = pkrtz(w1.z, w1.w);
        Wt[(bid * 4 + kt) * 64 + lane] = p;
    } else {
        const int n = (bid - 256) * 256 + tid;       // pair index [0, 4096)
        const float e = *epsp;
        const float2 A = *(const float2*)(X + 6 * n);      // x0 y0
        const float2 B = *(const float2*)(X + 6 * n + 2);  // z0 x1
        const float2 C = *(const float2*)(X + 6 * n + 4);  // y1 z1
        const float x0 = A.x * e, y0 = A.y * e, z0 = B.x * e;
        const float x1 = B.y * e, y1 = C.x * e, z1 = C.y * e;
        Cx[n] = pkrtz(-2.0f * x0, -2.0f * x1);
        Cy[n] = pkrtz(-2.0f * y0, -2.0f * y1);
        Cz[n] = pkrtz(-2.0f * z0, -2.0f * z1);
        Cc[n] = pkrtz(fmaf(x0, x0, fmaf(y0, y0, fmaf(z0, z0, 1.0f))),
                      fmaf(x1, x1, fmaf(y1, y1, fmaf(z1, z1, 1.0f))));
    }
}

// ---------------- main: 64 rows/block, 16-way split-N, LDS cross-wave reduce ------
// 256 blocks x 1024 threads (1 block/CU, 4 waves/SIMD). Each wave owns 4 row-tiles
// (64 rows) x a 512-point n-chunk (16 iterations of 32 points).
// WHY t=4: r2 showed both pipes <50% busy with per-CU cache traffic ~4 MiB —
// vector-memory-pipe (TA/L1 ~64 B/cyc/CU) bound at ~27 us. Same W-fragment +
// coord loads now feed 2x rows -> per-CU traffic halves to ~2 MiB.
// Register budget (4 waves/SIMD, unified file) = 128: acc[4][4]=64 (AGPR half)
// + ~60 arch. No explicit prefetch (r2 proved it's not the stall; no headroom).
__global__ __launch_bounds__(1024, 4) void rbf_main(
    const float* __restrict__ Xp, const uint4* __restrict__ Wt,
    const uint32_t* __restrict__ Cx, const uint32_t* __restrict__ Cy,
    const uint32_t* __restrict__ Cz, const uint32_t* __restrict__ Cc,
    const float* __restrict__ epsp, float* __restrict__ out)
{
    __shared__ __align__(16) float sR[4 * 64 * 64];   // 64 KB: [seg(4)][row(64)][col(64)]

    const int tid  = threadIdx.x;
    const int lane = tid & 63;
    const int wv   = tid >> 6;        // 0..15 = n-chunk
    const int m    = lane & 15;
    const int g    = lane >> 4;

    const int rowbase = blockIdx.x * 64;

    // per-lane row geometry for 4 tiles (rows rowbase + t*16 + m), f16 splat pairs
    const float e = *epsp;
    h2 pxk[4], pyk[4], pzk[4], aak[4];
    #pragma unroll
    for (int t = 0; t < 4; ++t) {
        const int r = rowbase + t * 16 + m;
        const float px = Xp[3 * r + 0] * e;
        const float py = Xp[3 * r + 1] * e;
        const float pz = Xp[3 * r + 2] * e;
        const float a  = fmaf(px, px, fmaf(py, py, pz * pz));
        pxk[t] = pkrtz2(px, px);
        pyk[t] = pkrtz2(py, py);
        pzk[t] = pkrtz2(pz, pz);
        aak[t] = pkrtz2(a, a);
    }
    const h2 mhf = {(_Float16)-0.5f, (_Float16)-0.5f};
    const h2 c15 = {(_Float16)1.5f, (_Float16)1.5f};

    f32x4 acc[4][4];
    #pragma unroll
    for (int t = 0; t < 4; ++t)
        #pragma unroll
        for (int kt = 0; kt < 4; ++kt)
            acc[t][kt] = (f32x4){0.f, 0.f, 0.f, 0.f};

    // uniform bases (wv, block only) — divergent part is a FIXED lane offset.
    // n-chunk: 512 points = 256 dwords per stream; s in [0,16), 16 dwords each.
    const uint32_t* cxp = Cx + wv * 256 + g * 4;   // + s*16 (imm)
    const uint32_t* cyp = Cy + wv * 256 + g * 4;
    const uint32_t* czp = Cz + wv * 256 + g * 4;
    const uint32_t* ccp = Cc + wv * 256 + g * 4;
    const uint4*    wp  = Wt + wv * 4096 + lane;   // + s*256 (SGPR) + kt*64 (imm)

    #pragma unroll 4
    for (int s = 0; s < 16; ++s) {
        const uint4 vx = *(const uint4*)(cxp + s * 16);
        const uint4 vy = *(const uint4*)(cyp + s * 16);
        const uint4 vz = *(const uint4*)(czp + s * 16);
        const uint4 vc = *(const uint4*)(ccp + s * 16);

        AF wf0, wf1, wf2, wf3;
        wf0.q = wp[s * 256];
        wf1.q = wp[s * 256 + 64];
        wf2.q = wp[s * 256 + 128];
        wf3.q = wp[s * 256 + 192];

        const h2 cx[4] = {__builtin_bit_cast(h2, vx.x), __builtin_bit_cast(h2, vx.y),
                          __builtin_bit_cast(h2, vx.z), __builtin_bit_cast(h2, vx.w)};
        const h2 cy[4] = {__builtin_bit_cast(h2, vy.x), __builtin_bit_cast(h2, vy.y),
                          __builtin_bit_cast(h2, vy.z), __builtin_bit_cast(h2, vy.w)};
        const h2 cz[4] = {__builtin_bit_cast(h2, vz.x), __builtin_bit_cast(h2, vz.y),
                          __builtin_bit_cast(h2, vz.z), __builtin_bit_cast(h2, vz.w)};
        const h2 cc[4] = {__builtin_bit_cast(h2, vc.x), __builtin_bit_cast(h2, vc.y),
                          __builtin_bit_cast(h2, vc.z), __builtin_bit_cast(h2, vc.w)};

        #pragma unroll
        for (int t = 0; t < 4; ++t) {
            AF af;
            #pragma unroll
            for (int j = 0; j < 4; ++j) {
                h2 d = cc[j] + aak[t];
                d = __builtin_elementwise_fma(pxk[t], cx[j], d);
                d = __builtin_elementwise_fma(pyk[t], cy[j], d);
                d = __builtin_elementwise_fma(pzk[t], cz[j], d);
                af.h[j] = pk_sqrt_fast(d, mhf, c15);
            }
            acc[t][0] = __builtin_amdgcn_mfma_f32_16x16x32_f16(af.v, wf0.v, acc[t][0], 0, 0, 0);
            acc[t][1] = __builtin_amdgcn_mfma_f32_16x16x32_f16(af.v, wf1.v, acc[t][1], 0, 0, 0);
            acc[t][2] = __builtin_amdgcn_mfma_f32_16x16x32_f16(af.v, wf2.v, acc[t][2], 0, 0, 0);
            acc[t][3] = __builtin_amdgcn_mfma_f32_16x16x32_f16(af.v, wf3.v, acc[t][3], 0, 0, 0);
        }
    }

    // ---- cross-wave reduction through LDS: 4 segs, sequential add phases ----
    // D layout: acc[t][kt][reg] = partial out[rowbase + t*16 + g*4 + reg][kt*16 + m]
    {
        float* base = sR + (wv & 3) * 4096;
        if (wv < 4) {
            #pragma unroll
            for (int t = 0; t < 4; ++t)
                #pragma unroll
                for (int kt = 0; kt < 4; ++kt)
                    #pragma unroll
                    for (int reg = 0; reg < 4; ++reg)
                        base[(t * 16 + g * 4 + reg) * 64 + kt * 16 + m] = acc[t][kt][reg];
        }
        __syncthreads();
        if (wv >= 4 && wv < 8) {
            #pragma unroll
            for (int t = 0; t < 4; ++t)
                #pragma unroll
                for (int kt = 0; kt < 4; ++kt)
                    #pragma unroll
                    for (int reg = 0; reg < 4; ++reg)
                        base[(t * 16 + g * 4 + reg) * 64 + kt * 16 + m] += acc[t][kt][reg];
        }
        __syncthreads();
        if (wv >= 8 && wv < 12) {
            #pragma unroll
            for (int t = 0; t < 4; ++t)
                #pragma unroll
                for (int kt = 0; kt < 4; ++kt)
                    #pragma unroll
                    for (int reg = 0; reg < 4; ++reg)
                        base[(t * 16 + g * 4 + reg) * 64 + kt * 16 + m] += acc[t][kt][reg];
        }
        __syncthreads();
        if (wv >= 12) {
            #pragma unroll
            for (int t = 0; t < 4; ++t)
                #pragma unroll
                for (int kt = 0; kt < 4; ++kt)
                    #pragma unroll
                    for (int reg = 0; reg < 4; ++reg)
                        base[(t * 16 + g * 4 + reg) * 64 + kt * 16 + m] += acc[t][kt][reg];
        }
        __syncthreads();
    }

    // 1024 threads: thread -> (row = tid>>4, kq = tid&15), sum 4 segments, store
    {
        const int row = tid >> 4;      // 0..63
        const int kq  = tid & 15;
        const float* p = sR + row * 64 + kq * 4;
        float4 s0 = *(const float4*)(p);
        #pragma unroll
        for (int w = 1; w < 4; ++w) {
            const float4 sw = *(const float4*)(p + w * 4096);
            s0.x += sw.x; s0.y += sw.y; s0.z += sw.z; s0.w += sw.w;
        }
        *(float4*)(out + (rowbase + row) * K_OUT + kq * 4) = s0;
    }
}

extern "C" void kernel_launch(void* const* d_in, const int* in_sizes, int n_in,
                              void* d_out, int out_size, void* d_ws, size_t ws_size,
                              hipStream_t stream) {
    (void)in_sizes; (void)n_in; (void)out_size; (void)ws_size;
    const float* Xp  = (const float*)d_in[0];   // (16384,3)
    const float* X   = (const float*)d_in[1];   // (8192,3)
    const float* Wf  = (const float*)d_in[2];   // (64,8192)
    const float* eps = (const float*)d_in[3];   // scalar
    float* out = (float*)d_out;                 // (16384,64)

    // ws: Wt (fragment-linear f16 W) 1 MiB | Cx,Cy,Cz,Cc 16 KiB each
    uint4*    Wt = (uint4*)d_ws;
    uint32_t* Cx = (uint32_t*)((char*)d_ws + (1u << 20));
    uint32_t* Cy = Cx + 4096;
    uint32_t* Cz = Cy + 4096;
    uint32_t* Cc = Cz + 4096;

    rbf_prep<<<dim3(272), dim3(256), 0, stream>>>(Wf, X, eps, Wt, Cx, Cy, Cz, Cc);
    rbf_main<<<dim3(M_ROWS / 64), dim3(1024), 0, stream>>>(
        Xp, Wt, Cx, Cy, Cz, Cc, eps, out);
}

// Round 4
// 96.078 us; speedup vs baseline: 1.9587x; 1.9587x over previous
//
#include <hip/hip_runtime.h>
#include <hip/hip_fp16.h>
#include <stdint.h>

// Problem constants: Xp(16384,3) X(8192,3) W(64,8192) eps scalar -> out(16384,64)
#define M_ROWS 16384
#define N_PTS  8192
#define K_OUT  64

typedef _Float16       h2    __attribute__((ext_vector_type(2)));
typedef unsigned short u16x2 __attribute__((ext_vector_type(2)));
typedef _Float16       f16x8 __attribute__((ext_vector_type(8)));
typedef float          f32x4 __attribute__((ext_vector_type(4)));

union AF { f16x8 v; uint4 q; uint32_t u[4]; h2 h[4]; };

__device__ __forceinline__ h2 pkrtz2(float a, float b) {
    return __builtin_bit_cast(h2, __builtin_amdgcn_cvt_pkrtz(a, b));
}
__device__ __forceinline__ uint32_t pkrtz(float a, float b) {
    return __builtin_bit_cast(uint32_t, __builtin_amdgcn_cvt_pkrtz(a, b));
}

// packed fast sqrt(t), t in [1, ~512]: per-half rsqrt bit-seed (0x59BA - (u>>1),
// packed 16-bit ops so no cross-half contamination) + 1 reassociated Newton:
// y = t*r0; p = y*r0; k = 1.5 - 0.5*p; phi = y*k.  6 packed VALU ops / 2 phis.
// Rel err <= ~3e-3 (validated: absmax 8 vs threshold 21.28).
__device__ __forceinline__ h2 pk_sqrt_fast(h2 t, h2 mhf, h2 c15) {
    u16x2 u = __builtin_bit_cast(u16x2, t);
    u16x2 r0u = (u16x2){0x59BA, 0x59BA} - (u >> 1);
    h2 r0 = __builtin_bit_cast(h2, r0u);
    h2 y = t * r0;
    h2 p = y * r0;
    h2 k = __builtin_elementwise_fma(p, mhf, c15);
    return y * k;
}

// ---------------- prep ----------------
// blocks [0,256):   W -> fragment-linear f16 Wt (B-frag order for 16x16x32):
//                   Wt uint4 idx (b*4+kt)*64+lane = W[kt*16+(lane&15)][b*32+(lane>>4)*8+j]
// blocks [256,272): coord streams as packed-f16 pairs (4096 dwords each):
//                   Cx = -2*eps*x, Cy, Cz, Cc = |eps*x|^2 + 1
__global__ __launch_bounds__(256) void rbf_prep(
    const float* __restrict__ Wf, const float* __restrict__ X,
    const float* __restrict__ epsp,
    uint4* __restrict__ Wt, uint32_t* __restrict__ Cx,
    uint32_t* __restrict__ Cy, uint32_t* __restrict__ Cz,
    uint32_t* __restrict__ Cc)
{
    const int bid = blockIdx.x, tid = threadIdx.x;
    if (bid < 256) {
        const int kt = tid >> 6, lane = tid & 63;
        const int l15 = lane & 15, g = lane >> 4;
        const int row = kt * 16 + l15;
        const int col = bid * 32 + g * 8;
        const float4* src = (const float4*)(Wf + row * N_PTS + col);
        const float4 w0 = src[0], w1 = src[1];
        uint4 p;
        p.x = pkrtz(w0.x, w0.y);
        p.y = pkrtz(w0.z, w0.w);
        p.z = pkrtz(w1.x, w1.y);
        p.w = pkrtz(w1.z, w1.w);
        Wt[(bid * 4 + kt) * 64 + lane] = p;
    } else {
        const int n = (bid - 256) * 256 + tid;       // pair index [0, 4096)
        const float e = *epsp;
        const float2 A = *(const float2*)(X + 6 * n);      // x0 y0
        const float2 B = *(const float2*)(X + 6 * n + 2);  // z0 x1
        const float2 C = *(const float2*)(X + 6 * n + 4);  // y1 z1
        const float x0 = A.x * e, y0 = A.y * e, z0 = B.x * e;
        const float x1 = B.y * e, y1 = C.x * e, z1 = C.y * e;
        Cx[n] = pkrtz(-2.0f * x0, -2.0f * x1);
        Cy[n] = pkrtz(-2.0f * y0, -2.0f * y1);
        Cz[n] = pkrtz(-2.0f * z0, -2.0f * z1);
        Cc[n] = pkrtz(fmaf(x0, x0, fmaf(y0, y0, fmaf(z0, z0, 1.0f))),
                      fmaf(x1, x1, fmaf(y1, y1, fmaf(z1, z1, 1.0f))));
    }
}

// one pipeline stage: build phi fragments from coord vectors + 16 MFMA (t=4)
__device__ __forceinline__ void rbf_step(
    const uint4& vx, const uint4& vy, const uint4& vz, const uint4& vc,
    const AF& wf0, const AF& wf1, const AF& wf2, const AF& wf3,
    const h2* pxk, const h2* pyk, const h2* pzk, const h2* aak,
    h2 mhf, h2 c15, f32x4 acc[4][4])
{
    const h2 cx[4] = {__builtin_bit_cast(h2, vx.x), __builtin_bit_cast(h2, vx.y),
                      __builtin_bit_cast(h2, vx.z), __builtin_bit_cast(h2, vx.w)};
    const h2 cy[4] = {__builtin_bit_cast(h2, vy.x), __builtin_bit_cast(h2, vy.y),
                      __builtin_bit_cast(h2, vy.z), __builtin_bit_cast(h2, vy.w)};
    const h2 cz[4] = {__builtin_bit_cast(h2, vz.x), __builtin_bit_cast(h2, vz.y),
                      __builtin_bit_cast(h2, vz.z), __builtin_bit_cast(h2, vz.w)};
    const h2 cc[4] = {__builtin_bit_cast(h2, vc.x), __builtin_bit_cast(h2, vc.y),
                      __builtin_bit_cast(h2, vc.z), __builtin_bit_cast(h2, vc.w)};

    #pragma unroll
    for (int t = 0; t < 4; ++t) {
        AF af;
        #pragma unroll
        for (int j = 0; j < 4; ++j) {
            h2 d = cc[j] + aak[t];
            d = __builtin_elementwise_fma(pxk[t], cx[j], d);
            d = __builtin_elementwise_fma(pyk[t], cy[j], d);
            d = __builtin_elementwise_fma(pzk[t], cz[j], d);
            af.h[j] = pk_sqrt_fast(d, mhf, c15);
        }
        acc[t][0] = __builtin_amdgcn_mfma_f32_16x16x32_f16(af.v, wf0.v, acc[t][0], 0, 0, 0);
        acc[t][1] = __builtin_amdgcn_mfma_f32_16x16x32_f16(af.v, wf1.v, acc[t][1], 0, 0, 0);
        acc[t][2] = __builtin_amdgcn_mfma_f32_16x16x32_f16(af.v, wf2.v, acc[t][2], 0, 0, 0);
        acc[t][3] = __builtin_amdgcn_mfma_f32_16x16x32_f16(af.v, wf3.v, acc[t][3], 0, 0, 0);
    }
}

// ---------------- main: 64 rows/block, 8-way split-N, LDS cross-wave reduce ------
// 256 blocks x 512 threads -> 1 block/CU BY GRID SIZE. Each wave owns ALL 64 block
// rows (t=4 tiles) x a 1024-point n-chunk (32 iters of 32 points).
// WHY t=4: r2 showed vector-memory-return-bound (~64 B/cyc/CU): 4 MiB/CU traffic
// -> 27 us floor, measured 42. Same 8 loads/iter now feed 16 MFMAs -> 2 MiB/CU.
// WHY (512,2): r3 proved t=4 needs ~175 regs (64 acc in unified file + ~110 arch);
// (1024,4)'s 128-budget spilled 470 MB to scratch. (512,2) -> 256-reg budget, no
// spill; occupancy 8 waves/CU (2/SIMD) is intentional - latency was proven
// non-binding in r2 (prefetch null), throughput is what matters.
// 1-deep register prefetch kept (regs plentiful; keeps TA fed during compute).
__global__ __launch_bounds__(512, 2) void rbf_main(
    const float* __restrict__ Xp, const uint4* __restrict__ Wt,
    const uint32_t* __restrict__ Cx, const uint32_t* __restrict__ Cy,
    const uint32_t* __restrict__ Cz, const uint32_t* __restrict__ Cc,
    const float* __restrict__ epsp, float* __restrict__ out)
{
    __shared__ __align__(16) float sR[4 * 64 * 64];   // 64 KB: [seg(4)][row(64)][col(64)]

    const int tid  = threadIdx.x;
    const int lane = tid & 63;
    const int wv   = tid >> 6;        // 0..7 = n-chunk
    const int m    = lane & 15;
    const int g    = lane >> 4;

    const int rowbase = blockIdx.x * 64;

    // per-lane row geometry for 4 tiles (rows rowbase + t*16 + m), f16 splat pairs
    const float e = *epsp;
    h2 pxk[4], pyk[4], pzk[4], aak[4];
    #pragma unroll
    for (int t = 0; t < 4; ++t) {
        const int r = rowbase + t * 16 + m;
        const float px = Xp[3 * r + 0] * e;
        const float py = Xp[3 * r + 1] * e;
        const float pz = Xp[3 * r + 2] * e;
        const float a  = fmaf(px, px, fmaf(py, py, pz * pz));
        pxk[t] = pkrtz2(px, px);
        pyk[t] = pkrtz2(py, py);
        pzk[t] = pkrtz2(pz, pz);
        aak[t] = pkrtz2(a, a);
    }
    const h2 mhf = {(_Float16)-0.5f, (_Float16)-0.5f};
    const h2 c15 = {(_Float16)1.5f, (_Float16)1.5f};

    f32x4 acc[4][4];
    #pragma unroll
    for (int t = 0; t < 4; ++t)
        #pragma unroll
        for (int kt = 0; kt < 4; ++kt)
            acc[t][kt] = (f32x4){0.f, 0.f, 0.f, 0.f};

    // uniform bases (wv, block only) — divergent part is a FIXED lane offset.
    // n-chunk: 1024 points = 512 dwords per stream; s in [0,32), 16 dwords each.
    const uint32_t* cxp = Cx + wv * 512 + g * 4;   // + s*16 (imm)
    const uint32_t* cyp = Cy + wv * 512 + g * 4;
    const uint32_t* czp = Cz + wv * 512 + g * 4;
    const uint32_t* ccp = Cc + wv * 512 + g * 4;
    const uint4*    wp  = Wt + wv * 8192 + lane;   // + s*256 (SGPR) + kt*64 (imm)

    // ---- software pipeline: prologue loads for s=0 ----
    uint4 vx = *(const uint4*)(cxp);
    uint4 vy = *(const uint4*)(cyp);
    uint4 vz = *(const uint4*)(czp);
    uint4 vc = *(const uint4*)(ccp);
    AF wf0, wf1, wf2, wf3;
    wf0.q = wp[0];
    wf1.q = wp[64];
    wf2.q = wp[128];
    wf3.q = wp[192];

    #pragma unroll 4
    for (int s = 0; s < 31; ++s) {
        const uint4 nvx = *(const uint4*)(cxp + (s + 1) * 16);
        const uint4 nvy = *(const uint4*)(cyp + (s + 1) * 16);
        const uint4 nvz = *(const uint4*)(czp + (s + 1) * 16);
        const uint4 nvc = *(const uint4*)(ccp + (s + 1) * 16);
        AF nw0, nw1, nw2, nw3;
        nw0.q = wp[(s + 1) * 256];
        nw1.q = wp[(s + 1) * 256 + 64];
        nw2.q = wp[(s + 1) * 256 + 128];
        nw3.q = wp[(s + 1) * 256 + 192];

        rbf_step(vx, vy, vz, vc, wf0, wf1, wf2, wf3,
                 pxk, pyk, pzk, aak, mhf, c15, acc);

        vx = nvx; vy = nvy; vz = nvz; vc = nvc;
        wf0 = nw0; wf1 = nw1; wf2 = nw2; wf3 = nw3;
    }
    rbf_step(vx, vy, vz, vc, wf0, wf1, wf2, wf3,
             pxk, pyk, pzk, aak, mhf, c15, acc);

    // ---- cross-wave reduction through LDS, two-phase over 4 segs ----
    // D layout: acc[t][kt][reg] = partial out[rowbase + t*16 + g*4 + reg][kt*16 + m]
    {
        float* base = sR + (wv & 3) * 4096;
        if (wv < 4) {
            #pragma unroll
            for (int t = 0; t < 4; ++t)
                #pragma unroll
                for (int kt = 0; kt < 4; ++kt)
                    #pragma unroll
                    for (int reg = 0; reg < 4; ++reg)
                        base[(t * 16 + g * 4 + reg) * 64 + kt * 16 + m] = acc[t][kt][reg];
        }
        __syncthreads();
        if (wv >= 4) {
            #pragma unroll
            for (int t = 0; t < 4; ++t)
                #pragma unroll
                for (int kt = 0; kt < 4; ++kt)
                    #pragma unroll
                    for (int reg = 0; reg < 4; ++reg)
                        base[(t * 16 + g * 4 + reg) * 64 + kt * 16 + m] += acc[t][kt][reg];
        }
        __syncthreads();
    }

    // 512 threads x 2 passes: thread -> (row, kq), sum 4 segments, store
    {
        const int kq = tid & 15;
        #pragma unroll
        for (int p2 = 0; p2 < 2; ++p2) {
            const int row = p2 * 32 + (tid >> 4);   // 0..63
            const float* p = sR + row * 64 + kq * 4;
            float4 s0 = *(const float4*)(p);
            #pragma unroll
            for (int w = 1; w < 4; ++w) {
                const float4 sw = *(const float4*)(p + w * 4096);
                s0.x += sw.x; s0.y += sw.y; s0.z += sw.z; s0.w += sw.w;
            }
            *(float4*)(out + (rowbase + row) * K_OUT + kq * 4) = s0;
        }
    }
}

extern "C" void kernel_launch(void* const* d_in, const int* in_sizes, int n_in,
                              void* d_out, int out_size, void* d_ws, size_t ws_size,
                              hipStream_t stream) {
    (void)in_sizes; (void)n_in; (void)out_size; (void)ws_size;
    const float* Xp  = (const float*)d_in[0];   // (16384,3)
    const float* X   = (const float*)d_in[1];   // (8192,3)
    const float* Wf  = (const float*)d_in[2];   // (64,8192)
    const float* eps = (const float*)d_in[3];   // scalar
    float* out = (float*)d_out;                 // (16384,64)

    // ws: Wt (fragment-linear f16 W) 1 MiB | Cx,Cy,Cz,Cc 16 KiB each
    uint4*    Wt = (uint4*)d_ws;
    uint32_t* Cx = (uint32_t*)((char*)d_ws + (1u << 20));
    uint32_t* Cy = Cx + 4096;
    uint32_t* Cz = Cy + 4096;
    uint32_t* Cc = Cz + 4096;

    rbf_prep<<<dim3(272), dim3(256), 0, stream>>>(Wf, X, eps, Wt, Cx, Cy, Cz, Cc);
    rbf_main<<<dim3(M_ROWS / 64), dim3(512), 0, stream>>>(
        Xp, Wt, Cx, Cy, Cz, Cc, eps, out);
}